// Round 1
// 138.081 us; speedup vs baseline: 1.0305x; 1.0305x over previous
//
#include <hip/hip_runtime.h>
#include <hip/hip_bf16.h>
#include <math.h>

// Problem constants: B=32 V=512 K=16 D=128 E=32 NE=8192 -> BV=16384 vertices
#define NLSTR 136   // LDS row stride (ushorts) for 16x128 tiles
#define ASTR  168   // LDS row stride (ushorts) for A tiles: 160+8 pad, 336B (16B-aligned)

typedef __bf16 bf16x8 __attribute__((ext_vector_type(8)));
typedef float f32x4 __attribute__((ext_vector_type(4)));
typedef float f32x16 __attribute__((ext_vector_type(16)));
typedef unsigned short ushort8v __attribute__((ext_vector_type(8)));

union FragU { ushort8v u; bf16x8 b; };

static __device__ inline unsigned short f2bf(float f){
  unsigned u = __float_as_uint(f);
  u += 0x7fffu + ((u >> 16) & 1u);   // RNE
  return (unsigned short)(u >> 16);
}
static __device__ inline float bf2f(unsigned short u){
  return __uint_as_float(((unsigned)u) << 16);
}
static __device__ inline unsigned pk2(float a, float b){
  union { __hip_bfloat162 h; unsigned u; } r;
  r.h = __float22bfloat162_rn(float2{a, b});
  return r.u;
}
static __device__ inline ushort8v pkcvt8(float4 a, float4 b){
  union { unsigned u[4]; ushort8v v; } r;
  r.u[0] = pk2(a.x, a.y); r.u[1] = pk2(a.z, a.w);
  r.u[2] = pk2(b.x, b.y); r.u[3] = pk2(b.z, b.w);
  return r.v;
}

// tanh-form GELU (max err ~3e-4 vs exact erf-GELU)
static __device__ inline float gelu_f(float x){
  float u = x * x;
  float p = fmaf(u, 0.07135481283f, 1.5957691216f);
  float t = x * p;
  float e = __builtin_amdgcn_exp2f(t * -1.44269504f);
  return x * __builtin_amdgcn_rcpf(1.0f + e);
}

// Raw barrier: publishes own LDS writes (lgkmcnt drain) WITHOUT draining vmcnt.
// __syncthreads() would emit s_waitcnt vmcnt(0) first, killing the gather prefetch.
#define WG_BARRIER() asm volatile("s_waitcnt lgkmcnt(0)\n\ts_barrier" ::: "memory")

// ---------------- prep: bf16 vertex table + fragment-order bf16 weights ----------------
// w1f: 32x32x16 B-frags, STRIP-MAJOR: frag (nc2*10+kc), elem j of lane:
//      W1[(nc2*32+(lane&31))*160 + kc*16 + (lane>>5)*8 + j]   (wave strip = contiguous 10KB)
// w2f/w3f: 16x16x32 B-frags as before.
__global__ __launch_bounds__(256) void prep_kernel(
    const float* __restrict__ vf, const float* __restrict__ W1,
    const float* __restrict__ W2, const float* __restrict__ W3,
    unsigned short* __restrict__ vfbf, unsigned short* __restrict__ w1f,
    unsigned short* __restrict__ w2f, unsigned short* __restrict__ w3f)
{
  int t = blockIdx.x * 256 + threadIdx.x;
  if (t < 262144){                       // 16384*128 / 8
    const float4* src = (const float4*)vf;
    float4 x = src[t * 2], y = src[t * 2 + 1];
    *(ushort8v*)(vfbf + t * 8) = pkcvt8(x, y);
    return;
  }
  int t2 = t - 262144;
  const float* s;
  unsigned short* d;
  if (t2 < 2560){                        // w1f: 4nc2 x 10kc strip-major
    int fragid = t2 >> 6, lane = t2 & 63;
    int nc2 = fragid / 10, kc = fragid % 10, n = lane & 31, h = lane >> 5;
    s = W1 + (nc2 * 32 + n) * 160 + kc * 16 + h * 8;
    d = w1f + t2 * 8;
  } else if (t2 < 6656){                 // w2f: 8kc x 8nc
    int t3 = t2 - 2560;
    int fragid = t3 >> 6, lane = t3 & 63;
    int kc = fragid >> 3, nc = fragid & 7, col = lane & 15, quad = lane >> 4;
    s = W2 + (nc * 16 + col) * 256 + kc * 32 + quad * 8;
    d = w2f + t3 * 8;
  } else if (t2 < 8704){                 // w3f: 4kc x 8nc
    int t3 = t2 - 6656;
    int fragid = t3 >> 6, lane = t3 & 63;
    int kc = fragid >> 3, nc = fragid & 7, col = lane & 15, quad = lane >> 4;
    s = W3 + (nc * 16 + col) * 128 + kc * 32 + quad * 8;
    d = w3f + t3 * 8;
  } else return;
#pragma unroll
  for (int j = 0; j < 8; j++) d[j] = f2bf(s[j]);
}

// ---------------- fused ----------------
// grid 1024 x 256thr. Block = 16 vertices = 8 pairs. B-in-registers (wave wid owns
// cols [wid*32,+32), 10 B-frags resident). A double-buffered in LDS. Schedule per
// pair p: RAW barrier (lgkm-only; in-flight gathers survive) -> commit p+1 (gathers
// ~2 iterations old) -> issue gathers p+2 -> hoisted LDS mask reads -> compute p
// (2 MFMA chains) -> epilogue. nbs masks staged in LDS once at start.
__global__ __launch_bounds__(256) void fused_kernel(
    const unsigned short* __restrict__ vfbf,
    const float* __restrict__ vf,
    const int* __restrict__ aadj, const int* __restrict__ badj,
    const float* __restrict__ edge, const float* __restrict__ nbs,
    const float* __restrict__ h0,
    const unsigned short* __restrict__ w1f, const unsigned short* __restrict__ w2f,
    const unsigned short* __restrict__ w3f,
    const float* __restrict__ b1, const float* __restrict__ b2, const float* __restrict__ b3,
    const float* __restrict__ lamda, const float* __restrict__ alpha,
    const int* __restrict__ lval,
    float* __restrict__ out)
{
  __shared__ __align__(16) unsigned short abuf[2][32 * ASTR];   // 2 x 10.5 KB
  __shared__ __align__(16) unsigned short nl_lds[16 * NLSTR];
  __shared__ __align__(16) unsigned short sup_lds[16 * NLSTR];
  __shared__ __align__(16) float nbs_lds[256];                  // 16 vertices x 16 masks
  const int wid  = threadIdx.x >> 6;
  const int lane = threadIdx.x & 63;
  const int n32  = lane & 31;
  const int h    = lane >> 5;
  const int col  = lane & 15;
  const int quad = lane >> 4;
  const int v0   = blockIdx.x * 16;

  // staging thread mapping: 8 threads per A row
  const int srow = threadIdx.x >> 3;   // 0..31: row (vertex-half + neighbor slot)
  const int ssub = threadIdx.x & 7;    // 0..7

  // ---- stage this block's nbs masks into LDS (1KB, published by first barrier) ----
  nbs_lds[threadIdx.x] = nbs[v0 * 16 + threadIdx.x];

  // ---- preload ALL pair indices (coalesced; kills idx->gather dependent chain) ----
  int a_all[8], e_all[8];
  {
    const int base = (v0 + (srow >> 4)) * 16 + (srow & 15);
#pragma unroll
    for (int p = 0; p < 8; p++){
      a_all[p] = aadj[base + 32 * p];
      e_all[p] = badj[base + 32 * p];
    }
  }

  // ---- B strip into registers (wave wid -> nc2 = wid), held all of stage 1 ----
  FragU bw[10];
#pragma unroll
  for (int kc = 0; kc < 10; kc++)
    bw[kc].u = *(const ushort8v*)(w1f + ((wid * 10 + kc) * 64 + lane) * 8);

  const float bb1 = b1[wid * 32 + n32];

  ushort8v sv0, sv1; float4 se;
  // issue pair-0 gathers
  {
    const ushort8v* vs = (const ushort8v*)(vfbf + (size_t)a_all[0] * 128 + ssub * 16);
    sv0 = vs[0]; sv1 = vs[1];
    se = *(const float4*)(edge + (size_t)e_all[0] * 32 + ssub * 4);
  }
  // commit pair-0 into abuf[0]
  {
    unsigned short* dst = abuf[0] + srow * ASTR + ssub * 16;
    *(ushort8v*)dst = sv0; *(ushort8v*)(dst + 8) = sv1;
    unsigned* ed = (unsigned*)(abuf[0] + srow * ASTR + 128 + ssub * 4);
    ed[0] = pk2(se.x, se.y); ed[1] = pk2(se.z, se.w);
  }
  // issue pair-1 gathers
  {
    const ushort8v* vs = (const ushort8v*)(vfbf + (size_t)a_all[1] * 128 + ssub * 16);
    sv0 = vs[0]; sv1 = vs[1];
    se = *(const float4*)(edge + (size_t)e_all[1] * 32 + ssub * 4);
  }

#pragma unroll
  for (int p = 0; p < 8; ++p){
    WG_BARRIER();   // publishes LDS writes; leaves gather loads in flight

    // ---- commit pair p+1 (gathers ~2 iterations old; compiler waits vmcnt here) ----
    if (p < 7){
      unsigned short* dst = abuf[(p + 1) & 1] + srow * ASTR + ssub * 16;
      *(ushort8v*)dst = sv0; *(ushort8v*)(dst + 8) = sv1;
      unsigned* ed = (unsigned*)(abuf[(p + 1) & 1] + srow * ASTR + 128 + ssub * 4);
      ed[0] = pk2(se.x, se.y); ed[1] = pk2(se.z, se.w);
    }
    // ---- issue gathers for pair p+2 ----
    if (p < 6){
      const ushort8v* vs = (const ushort8v*)(vfbf + (size_t)a_all[p + 2] * 128 + ssub * 16);
      sv0 = vs[0]; sv1 = vs[1];
      se = *(const float4*)(edge + (size_t)e_all[p + 2] * 32 + ssub * 4);
    }

    // ---- hoisted mask reads (LDS broadcast; latency hides under MFMA) ----
    const float4* nbsl = (const float4*)nbs_lds;
    const float4 mAlo = nbsl[8 * p + h],     mAhi = nbsl[8 * p + 2 + h];
    const float4 mBlo = nbsl[8 * p + 4 + h], mBhi = nbsl[8 * p + 6 + h];

    // ---- pair-p MFMA: A from LDS, B from registers; 2 accumulator chains ----
    const unsigned short* ab = abuf[p & 1] + n32 * ASTR + h * 8;
    f32x16 accA = {}, accB = {};
#pragma unroll
    for (int kc = 0; kc < 10; kc += 2){
      FragU fa0, fa1;
      fa0.u = *(const ushort8v*)(ab + kc * 16);
      fa1.u = *(const ushort8v*)(ab + (kc + 1) * 16);
      accA = __builtin_amdgcn_mfma_f32_32x32x16_bf16(fa0.b, bw[kc].b,     accA, 0, 0, 0);
      accB = __builtin_amdgcn_mfma_f32_32x32x16_bf16(fa1.b, bw[kc + 1].b, accB, 0, 0, 0);
    }
    f32x16 acc = accA + accB;

    // ---- epilogue: +b1, GELU, mask, reduce; C row=(reg&3)+8*(reg>>2)+4*h ----
    {
      float sA = gelu_f(acc[0] + bb1) * mAlo.x + gelu_f(acc[1] + bb1) * mAlo.y
               + gelu_f(acc[2] + bb1) * mAlo.z + gelu_f(acc[3] + bb1) * mAlo.w
               + gelu_f(acc[4] + bb1) * mAhi.x + gelu_f(acc[5] + bb1) * mAhi.y
               + gelu_f(acc[6] + bb1) * mAhi.z + gelu_f(acc[7] + bb1) * mAhi.w;
      float sB = gelu_f(acc[8] + bb1) * mBlo.x + gelu_f(acc[9] + bb1) * mBlo.y
               + gelu_f(acc[10] + bb1) * mBlo.z + gelu_f(acc[11] + bb1) * mBlo.w
               + gelu_f(acc[12] + bb1) * mBhi.x + gelu_f(acc[13] + bb1) * mBhi.y
               + gelu_f(acc[14] + bb1) * mBhi.z + gelu_f(acc[15] + bb1) * mBhi.w;
      sA += __shfl_xor(sA, 32, 64);
      sB += __shfl_xor(sB, 32, 64);
      if (h == 0) nl_lds[(2 * p)     * NLSTR + wid * 32 + n32] = f2bf(sA);
      else        nl_lds[(2 * p + 1) * NLSTR + wid * 32 + n32] = f2bf(sB);
    }
  }
  __syncthreads();

  // ---------------- stage 2: wave wid computes output cols [wid*32, wid*32+32) --------
  const int nc0 = 2 * wid;
  const float th = logf(lamda[0] / (float)lval[0] + 1.0f);
  const float al = alpha[0];

  // hoist h0 loads ahead of the MFMA loop (independent; latency hides under MFMA)
  float h0v[2][4];
#pragma unroll
  for (int pq = 0; pq < 2; pq++){
    const int d = (nc0 + pq) * 16 + col;
#pragma unroll
    for (int r = 0; r < 4; r++)
      h0v[pq][r] = h0[(v0 + quad * 4 + r) * 128 + d];
  }

  f32x4 acc2[2] = {};
#pragma unroll
  for (int kc = 0; kc < 8; kc++){
    FragU a;
    if (kc < 4) a.u = *(const ushort8v*)(nl_lds + col * NLSTR + kc * 32 + quad * 8);
    else        a.u = *(const ushort8v*)(vfbf + (size_t)(v0 + col) * 128 + (kc - 4) * 32 + quad * 8);
#pragma unroll
    for (int pq = 0; pq < 2; pq++){
      FragU bf_;
      bf_.u = *(const ushort8v*)(w2f + ((kc * 8 + nc0 + pq) * 64 + lane) * 8);
      acc2[pq] = __builtin_amdgcn_mfma_f32_16x16x32_bf16(a.b, bf_.b, acc2[pq], 0, 0, 0);
    }
  }

  float sup[2][4];
#pragma unroll
  for (int pq = 0; pq < 2; pq++){
    const int d = (nc0 + pq) * 16 + col;
    const float bb = b2[d];
#pragma unroll
    for (int r = 0; r < 4; r++){
      float hi = acc2[pq][r] + bb;
      float s = (1.f - al) * hi + al * h0v[pq][r];
      sup[pq][r] = s;
      sup_lds[(quad * 4 + r) * NLSTR + d] = f2bf(s);
    }
  }
  __syncthreads();

  // hoist fp32 residual loads (coalesced 64B segments; also closer to reference)
  float rv[2][4];
#pragma unroll
  for (int pq = 0; pq < 2; pq++){
    const int d = (nc0 + pq) * 16 + col;
#pragma unroll
    for (int r = 0; r < 4; r++)
      rv[pq][r] = vf[(size_t)(v0 + quad * 4 + r) * 128 + d];
  }

  f32x4 acc3[2] = {};
#pragma unroll
  for (int kc = 0; kc < 4; kc++){
    FragU a;
    a.u = *(const ushort8v*)(sup_lds + col * NLSTR + kc * 32 + quad * 8);
#pragma unroll
    for (int pq = 0; pq < 2; pq++){
      FragU bf_;
      bf_.u = *(const ushort8v*)(w3f + ((kc * 8 + nc0 + pq) * 64 + lane) * 8);
      acc3[pq] = __builtin_amdgcn_mfma_f32_16x16x32_bf16(a.b, bf_.b, acc3[pq], 0, 0, 0);
    }
  }

#pragma unroll
  for (int pq = 0; pq < 2; pq++){
    const int d = (nc0 + pq) * 16 + col;
    const float bb = b3[d];
#pragma unroll
    for (int r = 0; r < 4; r++){
      const int vtx = v0 + quad * 4 + r;
      out[vtx * 128 + d] = th * (acc3[pq][r] + bb) + (1.f - th) * sup[pq][r] + rv[pq][r];
    }
  }
}

extern "C" void kernel_launch(void* const* d_in, const int* in_sizes, int n_in,
                              void* d_out, int out_size, void* d_ws, size_t ws_size,
                              hipStream_t stream)
{
  const float* vfp  = (const float*)d_in[0];
  const int*   aadj = (const int*)d_in[1];
  const int*   badj = (const int*)d_in[2];
  const float* h0   = (const float*)d_in[3];
  const float* lam  = (const float*)d_in[4];
  const float* alp  = (const float*)d_in[5];
  const int*   lv   = (const int*)d_in[6];
  const float* edge = (const float*)d_in[7];
  // d_in[8] vertex_mask: unused by the reference math
  const float* nbs  = (const float*)d_in[9];
  const float* W1   = (const float*)d_in[10];
  const float* b1   = (const float*)d_in[11];
  const float* W2   = (const float*)d_in[12];
  const float* b2   = (const float*)d_in[13];
  const float* W3   = (const float*)d_in[14];
  const float* b3   = (const float*)d_in[15];
  float* out = (float*)d_out;

  // ws layout (ushorts): w1f [0,20480) | w2f [20480,53248) | w3f [53248,69632)
  //                      | vfbf [69632, 69632+2097152)
  unsigned short* w1f  = (unsigned short*)d_ws;
  unsigned short* w2f  = w1f + 20480;
  unsigned short* w3f  = w2f + 32768;
  unsigned short* vfbf = w3f + 16384;

  prep_kernel<<<1058, 256, 0, stream>>>(vfp, W1, W2, W3, vfbf, w1f, w2f, w3f);
  fused_kernel<<<1024, 256, 0, stream>>>(vfbf, vfp, aadj, badj, edge, nbs, h0,
                                         w1f, w2f, w3f, b1, b2, b3, lam, alp, lv, out);
}

// Round 3
// 135.204 us; speedup vs baseline: 1.0525x; 1.0213x over previous
//
#include <hip/hip_runtime.h>
#include <hip/hip_bf16.h>
#include <math.h>

// Problem constants: B=32 V=512 K=16 D=128 E=32 NE=8192 -> BV=16384 vertices
#define NLSTR 136   // LDS row stride (ushorts) for 16x128 tiles
#define ASTR  168   // LDS row stride (ushorts) for A tiles: 160+8 pad, 336B (16B-aligned)

typedef __bf16 bf16x8 __attribute__((ext_vector_type(8)));
typedef float f32x4 __attribute__((ext_vector_type(4)));
typedef float f32x16 __attribute__((ext_vector_type(16)));
typedef unsigned short ushort8v __attribute__((ext_vector_type(8)));

union FragU { ushort8v u; bf16x8 b; };

static __device__ inline unsigned short f2bf(float f){
  unsigned u = __float_as_uint(f);
  u += 0x7fffu + ((u >> 16) & 1u);   // RNE
  return (unsigned short)(u >> 16);
}
static __device__ inline float bf2f(unsigned short u){
  return __uint_as_float(((unsigned)u) << 16);
}
static __device__ inline unsigned pk2(float a, float b){
  union { __hip_bfloat162 h; unsigned u; } r;
  r.h = __float22bfloat162_rn(float2{a, b});
  return r.u;
}
static __device__ inline ushort8v pkcvt8(float4 a, float4 b){
  union { unsigned u[4]; ushort8v v; } r;
  r.u[0] = pk2(a.x, a.y); r.u[1] = pk2(a.z, a.w);
  r.u[2] = pk2(b.x, b.y); r.u[3] = pk2(b.z, b.w);
  return r.v;
}

// tanh-form GELU (max err ~3e-4 vs exact erf-GELU)
static __device__ inline float gelu_f(float x){
  float u = x * x;
  float p = fmaf(u, 0.07135481283f, 1.5957691216f);
  float t = x * p;
  float e = __builtin_amdgcn_exp2f(t * -1.44269504f);
  return x * __builtin_amdgcn_rcpf(1.0f + e);
}

// Raw barrier: publishes own LDS writes (lgkmcnt drain) WITHOUT draining vmcnt.
// __syncthreads() would emit s_waitcnt vmcnt(0) first, killing the gather prefetch.
#define WG_BARRIER() asm volatile("s_waitcnt lgkmcnt(0)\n\ts_barrier" ::: "memory")

// ---------------- prep: bf16 vertex table + fragment-order bf16 weights ----------------
__global__ __launch_bounds__(256) void prep_kernel(
    const float* __restrict__ vf, const float* __restrict__ W1,
    const float* __restrict__ W2, const float* __restrict__ W3,
    unsigned short* __restrict__ vfbf, unsigned short* __restrict__ w1f,
    unsigned short* __restrict__ w2f, unsigned short* __restrict__ w3f)
{
  int t = blockIdx.x * 256 + threadIdx.x;
  if (t < 262144){                       // 16384*128 / 8
    const float4* src = (const float4*)vf;
    float4 x = src[t * 2], y = src[t * 2 + 1];
    *(ushort8v*)(vfbf + t * 8) = pkcvt8(x, y);
    return;
  }
  int t2 = t - 262144;
  const float* s;
  unsigned short* d;
  if (t2 < 2560){                        // w1f: 4nc2 x 10kc strip-major
    int fragid = t2 >> 6, lane = t2 & 63;
    int nc2 = fragid / 10, kc = fragid % 10, n = lane & 31, h = lane >> 5;
    s = W1 + (nc2 * 32 + n) * 160 + kc * 16 + h * 8;
    d = w1f + t2 * 8;
  } else if (t2 < 6656){                 // w2f: 8kc x 8nc
    int t3 = t2 - 2560;
    int fragid = t3 >> 6, lane = t3 & 63;
    int kc = fragid >> 3, nc = fragid & 7, col = lane & 15, quad = lane >> 4;
    s = W2 + (nc * 16 + col) * 256 + kc * 32 + quad * 8;
    d = w2f + t3 * 8;
  } else if (t2 < 8704){                 // w3f: 4kc x 8nc
    int t3 = t2 - 6656;
    int fragid = t3 >> 6, lane = t3 & 63;
    int kc = fragid >> 3, nc = fragid & 7, col = lane & 15, quad = lane >> 4;
    s = W3 + (nc * 16 + col) * 128 + kc * 32 + quad * 8;
    d = w3f + t3 * 8;
  } else return;
#pragma unroll
  for (int j = 0; j < 8; j++) d[j] = f2bf(s[j]);
}

// ---------------- fused ----------------
// grid 1024 x 256thr. Block = 16 vertices = 8 pairs, processed as TWO 4-pair
// batches. abuf holds a full batch (4 x 10.5 KB, single-buffered). Schedule:
//   issue g(0..3) -> commit(0..3) -> BAR -> issue g(4..7)
//   -> compute p0..p3 (barrier-free: epilogue VALU of pair p overlaps MFMA of
//      pair p+1 on the same wave) -> BAR -> commit(4..7) -> BAR -> compute p4..p7
// 4 barriers total (vs 8). Gather latency is paid once per batch, hidden under
// a ~1500cy compute phase. LDS 52.7KB -> 3 blocks/CU; launch_bounds(256,3)
// pins the allocator to that occupancy.
__global__ __launch_bounds__(256, 3) void fused_kernel(
    const unsigned short* __restrict__ vfbf,
    const float* __restrict__ vf,
    const int* __restrict__ aadj, const int* __restrict__ badj,
    const float* __restrict__ edge, const float* __restrict__ nbs,
    const float* __restrict__ h0,
    const unsigned short* __restrict__ w1f, const unsigned short* __restrict__ w2f,
    const unsigned short* __restrict__ w3f,
    const float* __restrict__ b1, const float* __restrict__ b2, const float* __restrict__ b3,
    const float* __restrict__ lamda, const float* __restrict__ alpha,
    const int* __restrict__ lval,
    float* __restrict__ out)
{
  __shared__ __align__(16) unsigned short abuf[4][32 * ASTR];   // 4 x 10.5 KB
  __shared__ __align__(16) unsigned short nl_lds[16 * NLSTR];
  __shared__ __align__(16) unsigned short sup_lds[16 * NLSTR];
  __shared__ __align__(16) float nbs_lds[256];                  // 16 vertices x 16 masks
  const int wid  = threadIdx.x >> 6;
  const int lane = threadIdx.x & 63;
  const int n32  = lane & 31;
  const int h    = lane >> 5;
  const int col  = lane & 15;
  const int quad = lane >> 4;
  const int v0   = blockIdx.x * 16;

  // staging thread mapping: 8 threads per A row
  const int srow = threadIdx.x >> 3;   // 0..31: row (vertex-half + neighbor slot)
  const int ssub = threadIdx.x & 7;    // 0..7

  // ---- preload ALL pair indices (coalesced; kills idx->gather dependent chain) ----
  int a_all[8], e_all[8];
  {
    const int base = (v0 + (srow >> 4)) * 16 + (srow & 15);
#pragma unroll
    for (int p = 0; p < 8; p++){
      a_all[p] = aadj[base + 32 * p];
      e_all[p] = badj[base + 32 * p];
    }
  }

  ushort8v sv[4][2]; float4 se[4];
  // ---- issue batch-0 gathers (pairs 0..3) ----
#pragma unroll
  for (int q = 0; q < 4; q++){
    const ushort8v* vs = (const ushort8v*)(vfbf + (size_t)a_all[q] * 128 + ssub * 16);
    sv[q][0] = vs[0]; sv[q][1] = vs[1];
    se[q] = *(const float4*)(edge + (size_t)e_all[q] * 32 + ssub * 4);
  }

  // ---- stage nbs masks + B strip while batch-0 gathers fly ----
  nbs_lds[threadIdx.x] = nbs[v0 * 16 + threadIdx.x];

  FragU bw[10];
#pragma unroll
  for (int kc = 0; kc < 10; kc++)
    bw[kc].u = *(const ushort8v*)(w1f + ((wid * 10 + kc) * 64 + lane) * 8);

  const float bb1 = b1[wid * 32 + n32];

  // ---- commit batch 0 (vmcnt waits happen here, once) ----
#pragma unroll
  for (int q = 0; q < 4; q++){
    unsigned short* dst = abuf[q] + srow * ASTR + ssub * 16;
    *(ushort8v*)dst = sv[q][0]; *(ushort8v*)(dst + 8) = sv[q][1];
    unsigned* ed = (unsigned*)(abuf[q] + srow * ASTR + 128 + ssub * 4);
    ed[0] = pk2(se[q].x, se[q].y); ed[1] = pk2(se[q].z, se[q].w);
  }
  WG_BARRIER();   // publish batch 0 + nbs_lds; gathers not yet issued stay free

  // ---- issue batch-1 gathers (pairs 4..7); land during batch-0 compute ----
#pragma unroll
  for (int q = 0; q < 4; q++){
    const ushort8v* vs = (const ushort8v*)(vfbf + (size_t)a_all[q + 4] * 128 + ssub * 16);
    sv[q][0] = vs[0]; sv[q][1] = vs[1];
    se[q] = *(const float4*)(edge + (size_t)e_all[q + 4] * 32 + ssub * 4);
  }

  const float4* nbsl = (const float4*)nbs_lds;

  // ================= compute batch 0: pairs 0..3, barrier-free =================
#pragma unroll
  for (int p = 0; p < 4; p++){
    const float4 mAlo = nbsl[8 * p + h],     mAhi = nbsl[8 * p + 2 + h];
    const float4 mBlo = nbsl[8 * p + 4 + h], mBhi = nbsl[8 * p + 6 + h];
    const unsigned short* ab = abuf[p] + n32 * ASTR + h * 8;
    f32x16 accA = {}, accB = {};
#pragma unroll
    for (int kc = 0; kc < 10; kc += 2){
      FragU fa0, fa1;
      fa0.u = *(const ushort8v*)(ab + kc * 16);
      fa1.u = *(const ushort8v*)(ab + (kc + 1) * 16);
      accA = __builtin_amdgcn_mfma_f32_32x32x16_bf16(fa0.b, bw[kc].b,     accA, 0, 0, 0);
      accB = __builtin_amdgcn_mfma_f32_32x32x16_bf16(fa1.b, bw[kc + 1].b, accB, 0, 0, 0);
    }
    f32x16 acc = accA + accB;
    float sA = gelu_f(acc[0] + bb1) * mAlo.x + gelu_f(acc[1] + bb1) * mAlo.y
             + gelu_f(acc[2] + bb1) * mAlo.z + gelu_f(acc[3] + bb1) * mAlo.w
             + gelu_f(acc[4] + bb1) * mAhi.x + gelu_f(acc[5] + bb1) * mAhi.y
             + gelu_f(acc[6] + bb1) * mAhi.z + gelu_f(acc[7] + bb1) * mAhi.w;
    float sB = gelu_f(acc[8] + bb1) * mBlo.x + gelu_f(acc[9] + bb1) * mBlo.y
             + gelu_f(acc[10] + bb1) * mBlo.z + gelu_f(acc[11] + bb1) * mBlo.w
             + gelu_f(acc[12] + bb1) * mBhi.x + gelu_f(acc[13] + bb1) * mBhi.y
             + gelu_f(acc[14] + bb1) * mBhi.z + gelu_f(acc[15] + bb1) * mBhi.w;
    sA += __shfl_xor(sA, 32, 64);
    sB += __shfl_xor(sB, 32, 64);
    if (h == 0) nl_lds[(2 * p)     * NLSTR + wid * 32 + n32] = f2bf(sA);
    else        nl_lds[(2 * p + 1) * NLSTR + wid * 32 + n32] = f2bf(sB);
  }
  WG_BARRIER();   // all waves done reading abuf (own lgkm drained before barrier)

  // ---- commit batch 1 ----
#pragma unroll
  for (int q = 0; q < 4; q++){
    unsigned short* dst = abuf[q] + srow * ASTR + ssub * 16;
    *(ushort8v*)dst = sv[q][0]; *(ushort8v*)(dst + 8) = sv[q][1];
    unsigned* ed = (unsigned*)(abuf[q] + srow * ASTR + 128 + ssub * 4);
    ed[0] = pk2(se[q].x, se[q].y); ed[1] = pk2(se[q].z, se[q].w);
  }
  WG_BARRIER();   // publish batch 1

  // ================= compute batch 1: pairs 4..7 =================
#pragma unroll
  for (int p = 0; p < 4; p++){
    const int pp = p + 4;
    const float4 mAlo = nbsl[8 * pp + h],     mAhi = nbsl[8 * pp + 2 + h];
    const float4 mBlo = nbsl[8 * pp + 4 + h], mBhi = nbsl[8 * pp + 6 + h];
    const unsigned short* ab = abuf[p] + n32 * ASTR + h * 8;
    f32x16 accA = {}, accB = {};
#pragma unroll
    for (int kc = 0; kc < 10; kc += 2){
      FragU fa0, fa1;
      fa0.u = *(const ushort8v*)(ab + kc * 16);
      fa1.u = *(const ushort8v*)(ab + (kc + 1) * 16);
      accA = __builtin_amdgcn_mfma_f32_32x32x16_bf16(fa0.b, bw[kc].b,     accA, 0, 0, 0);
      accB = __builtin_amdgcn_mfma_f32_32x32x16_bf16(fa1.b, bw[kc + 1].b, accB, 0, 0, 0);
    }
    f32x16 acc = accA + accB;
    float sA = gelu_f(acc[0] + bb1) * mAlo.x + gelu_f(acc[1] + bb1) * mAlo.y
             + gelu_f(acc[2] + bb1) * mAlo.z + gelu_f(acc[3] + bb1) * mAlo.w
             + gelu_f(acc[4] + bb1) * mAhi.x + gelu_f(acc[5] + bb1) * mAhi.y
             + gelu_f(acc[6] + bb1) * mAhi.z + gelu_f(acc[7] + bb1) * mAhi.w;
    float sB = gelu_f(acc[8] + bb1) * mBlo.x + gelu_f(acc[9] + bb1) * mBlo.y
             + gelu_f(acc[10] + bb1) * mBlo.z + gelu_f(acc[11] + bb1) * mBlo.w
             + gelu_f(acc[12] + bb1) * mBhi.x + gelu_f(acc[13] + bb1) * mBhi.y
             + gelu_f(acc[14] + bb1) * mBhi.z + gelu_f(acc[15] + bb1) * mBhi.w;
    sA += __shfl_xor(sA, 32, 64);
    sB += __shfl_xor(sB, 32, 64);
    if (h == 0) nl_lds[(2 * pp)     * NLSTR + wid * 32 + n32] = f2bf(sA);
    else        nl_lds[(2 * pp + 1) * NLSTR + wid * 32 + n32] = f2bf(sB);
  }
  __syncthreads();

  // ---------------- stage 2: wave wid computes output cols [wid*32, wid*32+32) --------
  const int nc0 = 2 * wid;
  const float th = logf(lamda[0] / (float)lval[0] + 1.0f);
  const float al = alpha[0];

  // hoist h0 loads ahead of the MFMA loop (independent; latency hides under MFMA)
  float h0v[2][4];
#pragma unroll
  for (int pq = 0; pq < 2; pq++){
    const int d = (nc0 + pq) * 16 + col;
#pragma unroll
    for (int r = 0; r < 4; r++)
      h0v[pq][r] = h0[(v0 + quad * 4 + r) * 128 + d];
  }

  f32x4 acc2[2] = {};
#pragma unroll
  for (int kc = 0; kc < 8; kc++){
    FragU a;
    if (kc < 4) a.u = *(const ushort8v*)(nl_lds + col * NLSTR + kc * 32 + quad * 8);
    else        a.u = *(const ushort8v*)(vfbf + (size_t)(v0 + col) * 128 + (kc - 4) * 32 + quad * 8);
#pragma unroll
    for (int pq = 0; pq < 2; pq++){
      FragU bf_;
      bf_.u = *(const ushort8v*)(w2f + ((kc * 8 + nc0 + pq) * 64 + lane) * 8);
      acc2[pq] = __builtin_amdgcn_mfma_f32_16x16x32_bf16(a.b, bf_.b, acc2[pq], 0, 0, 0);
    }
  }

  float sup[2][4];
#pragma unroll
  for (int pq = 0; pq < 2; pq++){
    const int d = (nc0 + pq) * 16 + col;
    const float bb = b2[d];
#pragma unroll
    for (int r = 0; r < 4; r++){
      float hi = acc2[pq][r] + bb;
      float s = (1.f - al) * hi + al * h0v[pq][r];
      sup[pq][r] = s;
      sup_lds[(quad * 4 + r) * NLSTR + d] = f2bf(s);
    }
  }
  __syncthreads();

  // hoist fp32 residual loads (coalesced 64B segments)
  float rv[2][4];
#pragma unroll
  for (int pq = 0; pq < 2; pq++){
    const int d = (nc0 + pq) * 16 + col;
#pragma unroll
    for (int r = 0; r < 4; r++)
      rv[pq][r] = vf[(size_t)(v0 + quad * 4 + r) * 128 + d];
  }

  f32x4 acc3[2] = {};
#pragma unroll
  for (int kc = 0; kc < 4; kc++){
    FragU a;
    a.u = *(const ushort8v*)(sup_lds + col * NLSTR + kc * 32 + quad * 8);
#pragma unroll
    for (int pq = 0; pq < 2; pq++){
      FragU bf_;
      bf_.u = *(const ushort8v*)(w3f + ((kc * 8 + nc0 + pq) * 64 + lane) * 8);
      acc3[pq] = __builtin_amdgcn_mfma_f32_16x16x32_bf16(a.b, bf_.b, acc3[pq], 0, 0, 0);
    }
  }

#pragma unroll
  for (int pq = 0; pq < 2; pq++){
    const int d = (nc0 + pq) * 16 + col;
    const float bb = b3[d];
#pragma unroll
    for (int r = 0; r < 4; r++){
      const int vtx = v0 + quad * 4 + r;
      out[vtx * 128 + d] = th * (acc3[pq][r] + bb) + (1.f - th) * sup[pq][r] + rv[pq][r];
    }
  }
}

extern "C" void kernel_launch(void* const* d_in, const int* in_sizes, int n_in,
                              void* d_out, int out_size, void* d_ws, size_t ws_size,
                              hipStream_t stream)
{
  const float* vfp  = (const float*)d_in[0];
  const int*   aadj = (const int*)d_in[1];
  const int*   badj = (const int*)d_in[2];
  const float* h0   = (const float*)d_in[3];
  const float* lam  = (const float*)d_in[4];
  const float* alp  = (const float*)d_in[5];
  const int*   lv   = (const int*)d_in[6];
  const float* edge = (const float*)d_in[7];
  // d_in[8] vertex_mask: unused by the reference math
  const float* nbs  = (const float*)d_in[9];
  const float* W1   = (const float*)d_in[10];
  const float* b1   = (const float*)d_in[11];
  const float* W2   = (const float*)d_in[12];
  const float* b2   = (const float*)d_in[13];
  const float* W3   = (const float*)d_in[14];
  const float* b3   = (const float*)d_in[15];
  float* out = (float*)d_out;

  // ws layout (ushorts): w1f [0,20480) | w2f [20480,53248) | w3f [53248,69632)
  //                      | vfbf [69632, 69632+2097152)
  unsigned short* w1f  = (unsigned short*)d_ws;
  unsigned short* w2f  = w1f + 20480;
  unsigned short* w3f  = w2f + 32768;
  unsigned short* vfbf = w3f + 16384;

  prep_kernel<<<1058, 256, 0, stream>>>(vfp, W1, W2, W3, vfbf, w1f, w2f, w3f);
  fused_kernel<<<1024, 256, 0, stream>>>(vfbf, vfp, aadj, badj, edge, nbs, h0,
                                         w1f, w2f, w3f, b1, b2, b3, lam, alp, lv, out);
}